// Round 15
// baseline (177.827 us; speedup 1.0000x reference)
//
#include <hip/hip_runtime.h>
#include <stdint.h>

#define B_   16
#define N_   100
#define D_   1024
#define L_   2000
#define M_   1600      // B_*N_

#define RCAP 24
#define ZMAX 2400
#define TC   12        // task chunk in k_mix (static unroll bound — keeps acc[] in VGPRs)

typedef __bf16 bf16x8 __attribute__((ext_vector_type(8)));
typedef float  f32x4  __attribute__((ext_vector_type(4)));

__device__ __forceinline__ void gl_lds16(const __bf16* g, __bf16* l) {
    __builtin_amdgcn_global_load_lds(
        (const __attribute__((address_space(1))) void*)g,
        (__attribute__((address_space(3))) void*)l, 16, 0, 0);
}

// ---------------- prep: f32 -> bf16 conversions (feature, wcat, biasB) ----------------

__global__ void __launch_bounds__(256)
k_prep(const float* __restrict__ f,
       const float* __restrict__ W0, const float* __restrict__ W1,
       const float* __restrict__ Wa, const float* __restrict__ Wb,
       const float* __restrict__ bias,
       __bf16* __restrict__ fb, __bf16* __restrict__ wcat, __bf16* __restrict__ biasB) {
    int i = blockIdx.x * 256 + threadIdx.x;      // < 854016 exactly (3336*256)
    union { __bf16 h[8]; uint4 u; } pk;
    if (i < 204800) {
        long base = (long)i * 8;
        const float4* p = (const float4*)(f + base);
        float4 x = p[0], y = p[1];
        pk.h[0]=(__bf16)x.x; pk.h[1]=(__bf16)x.y; pk.h[2]=(__bf16)x.z; pk.h[3]=(__bf16)x.w;
        pk.h[4]=(__bf16)y.x; pk.h[5]=(__bf16)y.y; pk.h[6]=(__bf16)y.z; pk.h[7]=(__bf16)y.w;
        ((uint4*)fb)[i] = pk.u;
    } else if (i < 598016) {
        int j = i - 204800;
        long base = (long)j * 8;
        long seg = base >> 20;
        long off = base & ((1l << 20) - 1);
        if (seg == 0) {
            const float4* p0 = (const float4*)(W0 + off);
            const float4* p1 = (const float4*)(W1 + off);
            float4 a0 = p0[0], a1 = p0[1], b0 = p1[0], b1 = p1[1];
            pk.h[0]=(__bf16)(a0.x+b0.x); pk.h[1]=(__bf16)(a0.y+b0.y);
            pk.h[2]=(__bf16)(a0.z+b0.z); pk.h[3]=(__bf16)(a0.w+b0.w);
            pk.h[4]=(__bf16)(a1.x+b1.x); pk.h[5]=(__bf16)(a1.y+b1.y);
            pk.h[6]=(__bf16)(a1.z+b1.z); pk.h[7]=(__bf16)(a1.w+b1.w);
        } else {
            const float* src = (seg == 1) ? Wa : Wb;
            const float4* p = (const float4*)(src + off);
            float4 x = p[0], y = p[1];
            pk.h[0]=(__bf16)x.x; pk.h[1]=(__bf16)x.y; pk.h[2]=(__bf16)x.z; pk.h[3]=(__bf16)x.w;
            pk.h[4]=(__bf16)y.x; pk.h[5]=(__bf16)y.y; pk.h[6]=(__bf16)y.z; pk.h[7]=(__bf16)y.w;
        }
        ((uint4*)wcat)[j] = pk.u;
    } else {
        int j = i - 598016;                  // < 256000
        long base = (long)j * 8;
        const float4* p = (const float4*)(bias + base);
        float4 x = p[0], y = p[1];
        pk.h[0]=(__bf16)x.x; pk.h[1]=(__bf16)x.y; pk.h[2]=(__bf16)x.z; pk.h[3]=(__bf16)x.w;
        pk.h[4]=(__bf16)y.x; pk.h[5]=(__bf16)y.y; pk.h[6]=(__bf16)y.z; pk.h[7]=(__bf16)y.w;
        ((uint4*)biasB)[j] = pk.u;
    }
}

// -------- main GEMM: [1600 x 3072] = fb @ wcat^T, 600 uniform blocks, XCD-swizzled --------

#define BM 64
#define BN 128
#define BK 64

__global__ void __launch_bounds__(256)
k_gemm(const __bf16* __restrict__ fb, const __bf16* __restrict__ wcat,
       const float* __restrict__ feat, const float* __restrict__ ba,
       const float* __restrict__ bbias,
       float* __restrict__ out0, float* __restrict__ aB, float* __restrict__ bB) {
    __shared__ __align__(16) __bf16 As[BM * BK];   // 8 KB
    __shared__ __align__(16) __bf16 Bs[BN * BK];   // 16 KB
    int t = threadIdx.x;
    int pid = blockIdx.x;
    int lane = t & 63, wave = t >> 6;
    int wr = wave & 1, wc = wave >> 1;
    int lrow = lane & 15, quad = lane >> 4;

    int v = (pid & 7) * 75 + (pid >> 3);       // [0,600) unique
    int bn = v / 25, bm = v % 25;              // per-XCD: bn in [3x,3x+3)
    const __bf16* Ag = fb   + (long)(bm * BM) * D_;
    const __bf16* Bg = wcat + (long)(bn * BN) * D_;

    f32x4 acc[2][4] = {};
    for (int k0 = 0; k0 < D_; k0 += BK) {
        #pragma unroll
        for (int pi = 0; pi < 2; ++pi) {
            int p = pi * 256 + t, row = p >> 3, c = (p & 7) ^ (row & 7);
            gl_lds16(Ag + (long)row * D_ + k0 + c * 8, As + p * 8);
        }
        #pragma unroll
        for (int pi = 0; pi < 4; ++pi) {
            int p = pi * 256 + t, row = p >> 3, c = (p & 7) ^ (row & 7);
            gl_lds16(Bg + (long)row * D_ + k0 + c * 8, Bs + p * 8);
        }
        __syncthreads();
        #pragma unroll
        for (int ks = 0; ks < 2; ++ks) {
            bf16x8 af[2], bf[4];
            #pragma unroll
            for (int i = 0; i < 2; ++i) {
                int r = wr * 32 + i * 16 + lrow;
                int slot = r * 8 + (((ks << 2) | quad) ^ (r & 7));
                af[i] = *(const bf16x8*)(As + slot * 8);
            }
            #pragma unroll
            for (int j = 0; j < 4; ++j) {
                int r = wc * 64 + j * 16 + lrow;
                int slot = r * 8 + (((ks << 2) | quad) ^ (r & 7));
                bf[j] = *(const bf16x8*)(Bs + slot * 8);
            }
            #pragma unroll
            for (int i = 0; i < 2; ++i)
                #pragma unroll
                for (int j = 0; j < 4; ++j)
                    acc[i][j] = __builtin_amdgcn_mfma_f32_16x16x32_bf16(af[i], bf[j], acc[i][j], 0, 0, 0);
        }
        __syncthreads();
    }

    int nbase = bn * BN;
    int seg = bn >> 3;
    #pragma unroll
    for (int i = 0; i < 2; ++i) {
        int gm0 = bm * BM + wr * 32 + i * 16 + quad * 4;
        #pragma unroll
        for (int j = 0; j < 4; ++j) {
            int col = (nbase + wc * 64 + j * 16 + lrow) & 1023;
            #pragma unroll
            for (int r = 0; r < 4; ++r) {
                long m = gm0 + r;
                float v2 = acc[i][j][r];
                if (seg == 0)      out0[m * D_ + col] = v2 + feat[m * D_ + col];
                else if (seg == 1) aB[m * D_ + col]   = v2 + ba[col];
                else               bB[m * D_ + col]   = v2 + bbias[col];
            }
        }
    }
}

// ---- merged dispatch: alpha weights ∪ XCD-sliced bias gather (both depend only on gemm) ----
// pids [0,400):   alpha (b, kc): corr -> wl/cwG. Dirty rows ranked by ascending row index.
// pids [400,2000): gather: gp=pid-400; ds=gp&7 (aligns with XCD=pid%8 -> biasB d-slice
//                  512 KB stays L2-resident per XCD); rg=gp>>3: rows [8rg, 8rg+8).
//                  out0[bi, ds*128..+128) += sum_j biasB[graph[bi,j], dslice].

__global__ void __launch_bounds__(256)
k_ga(const int* __restrict__ graph, const float* __restrict__ aB,
     const float* __restrict__ bB, const __bf16* __restrict__ biasB,
     float* __restrict__ out0, float* __restrict__ wl, float* __restrict__ cwG) {
    __shared__ int rowCnt[N_], rowOff[N_], rowRank[N_];
    __shared__ int ndvS, totZS;
    __shared__ int zjL[ZMAX];                 // gather path reuses as idxs[800]
    __shared__ short prL[ZMAX];
    __shared__ float corrL[RCAP][4];
    __shared__ float wred[4][4];

    int pid = blockIdx.x, t = threadIdx.x;

    if (pid >= 400) {
        // -------- gather path --------
        int gp = pid - 400;
        int ds = gp & 7, rg = gp >> 3;        // ds<8, rg<200
        int r = t >> 5, cp = t & 31;          // r<8 rows, cp<32 col-quads
        for (int idx = t; idx < 800; idx += 256)
            zjL[idx] = graph[(long)(rg * 8 + idx / 100) * N_ + idx % 100];
        __syncthreads();
        const __bf16* bp = biasB + ds * 128 + cp * 4;
        const int* my = zjL + r * 100;
        float a0 = 0.f, a1 = 0.f, a2 = 0.f, a3 = 0.f;
        #pragma unroll 4
        for (int j = 0; j < N_; ++j) {
            int lb = my[j];
            union { uint2 u; __bf16 h[4]; } pk;
            pk.u = *(const uint2*)(bp + (long)lb * D_);
            a0 += (float)pk.h[0]; a1 += (float)pk.h[1];
            a2 += (float)pk.h[2]; a3 += (float)pk.h[3];
        }
        long bi = rg * 8 + r;
        float4* o = (float4*)(out0 + bi * D_ + ds * 128 + cp * 4);
        float4 cur = *o;
        cur.x += a0; cur.y += a1; cur.z += a2; cur.w += a3;
        *o = cur;
        return;
    }

    // -------- alpha path --------
    int b = pid / 25, kc = pid - b * 25;
    int lane = t & 63, wave = t >> 6;

    const int* g = graph + (long)b * N_ * N_;
    if (t < N_) {
        int c = 0;
        for (int j = 0; j < N_; ++j) if (g[t * N_ + j] == 0) ++c;
        rowCnt[t] = c;
    }
    if (t < RCAP * 4) corrL[t >> 2][t & 3] = 0.f;
    __syncthreads();
    if (t == 0) {
        int off = 0, rank = 0;
        for (int i = 0; i < N_; ++i) {
            if (rowCnt[i] > 0 && rank < RCAP) {
                rowRank[i] = rank; rowOff[i] = off; off += rowCnt[i]; ++rank;
            } else rowRank[i] = -1;
        }
        ndvS = rank; totZS = off;
    }
    __syncthreads();
    if (t < N_ && rowRank[t] >= 0) {
        int pos = rowOff[t], r = rowRank[t];
        for (int j = 0; j < N_; ++j)
            if (g[t * N_ + j] == 0) { zjL[pos] = j; prL[pos] = (short)r; ++pos; }
    }
    __syncthreads();
    int Z = totZS, ndv = ndvS;

    int k0 = kc * 4;
    float4 bv[4];
    #pragma unroll
    for (int kk = 0; kk < 4; ++kk)
        bv[kk] = *(const float4*)(bB + ((long)(b * N_ + k0 + kk)) * D_ + t * 4);

    for (int q = 0; q < Z; ++q) {
        const float* ar = aB + ((long)(b * N_ + zjL[q])) * D_;
        float4 av = *(const float4*)(ar + t * 4);
        float s[4];
        #pragma unroll
        for (int kk = 0; kk < 4; ++kk)
            s[kk] = av.x * bv[kk].x + av.y * bv[kk].y + av.z * bv[kk].z + av.w * bv[kk].w;
        #pragma unroll
        for (int off = 32; off > 0; off >>= 1)
            #pragma unroll
            for (int kk = 0; kk < 4; ++kk) s[kk] += __shfl_xor(s[kk], off);
        if (lane == 0) { wred[wave][0]=s[0]; wred[wave][1]=s[1]; wred[wave][2]=s[2]; wred[wave][3]=s[3]; }
        __syncthreads();
        if (t < 4) {
            float v = wred[0][t] + wred[1][t] + wred[2][t] + wred[3][t];
            corrL[prL[q]][t] += fmaxf(v, 0.f);
        }
        __syncthreads();
    }

    if (t < 4) {
        int k = k0 + t;
        float denom = (float)(N_ - ndv);
        for (int r = 0; r < ndv; ++r) {
            float e = __expf(-corrL[r][t]);
            corrL[r][t] = e;
            denom += e;
        }
        float w = 1.f / denom;
        wl[b * N_ + k] = w;
        for (int r = 0; r < ndv; ++r)
            cwG[((long)b * RCAP + r) * N_ + k] = corrL[r][t] * w;
    }
}

// ---------------- mix: out rows = weighted sums of out0 rows (float4) ----------------

__global__ void __launch_bounds__(256)
k_mix(const int* __restrict__ graph, const float* __restrict__ wl,
      const float* __restrict__ cwG, const float* __restrict__ out0,
      float* __restrict__ out) {
    int b = blockIdx.x, dq = blockIdx.y;
    int t = threadIdx.x, c4 = t & 63, q = t >> 6;
    int d0 = dq * 256;
    __shared__ int hasZ[N_], mapL[N_], ndvS;
    __shared__ float wT[TC][N_];
    __shared__ f32x4 parts[4][TC][64];

    const int* g = graph + (long)b * N_ * N_;
    if (t < N_) {
        int z = 0;
        for (int j = 0; j < N_; ++j) if (g[t * N_ + j] == 0) { z = 1; break; }
        hasZ[t] = z;
    }
    __syncthreads();
    if (t < N_) {
        int rank = 0;
        for (int i = 0; i < t; ++i) rank += hasZ[i];
        mapL[t] = (hasZ[t] && rank < RCAP) ? 1 + rank : 0;
    }
    if (t == 0) {
        int n = 0;
        for (int i = 0; i < N_; ++i) n += hasZ[i];
        ndvS = min(n, RCAP);
    }
    __syncthreads();
    int ndv = ndvS, ntask = ndv + 1;

    const float* o0 = out0 + (long)b * N_ * D_ + d0;
    for (int cb = 0; cb < ntask; cb += TC) {
        for (int idx = t; idx < TC * N_; idx += 256) {
            int rr = idx / N_, j = idx - rr * N_;
            int task = cb + rr;
            float v = 0.f;
            if (task == 0)         v = wl[b * N_ + j];
            else if (task <= ndv)  v = cwG[((long)b * RCAP + task - 1) * N_ + j];
            wT[rr][j] = v;
        }
        __syncthreads();
        f32x4 acc[TC] = {};
        for (int j = q * 25; j < q * 25 + 25; ++j) {
            f32x4 v = *(const f32x4*)(o0 + (long)j * D_ + c4 * 4);
            #pragma unroll
            for (int rr = 0; rr < TC; ++rr) acc[rr] += wT[rr][j] * v;
        }
        #pragma unroll
        for (int rr = 0; rr < TC; ++rr) parts[q][rr][c4] = acc[rr];
        __syncthreads();
        for (int i = q * 25; i < q * 25 + 25; ++i) {
            int task = mapL[i];
            if (task >= cb && task < cb + TC) {
                int rr = task - cb;
                f32x4 s = parts[0][rr][c4] + parts[1][rr][c4]
                        + parts[2][rr][c4] + parts[3][rr][c4];
                *(f32x4*)(out + ((long)(b * N_ + i)) * D_ + d0 + c4 * 4) = s;
            }
        }
        __syncthreads();
    }
}

// ---------------- launch ----------------

extern "C" void kernel_launch(void* const* d_in, const int* in_sizes, int n_in,
                              void* d_out, int out_size, void* d_ws, size_t ws_size,
                              hipStream_t stream) {
    const float* feature = (const float*)d_in[0];
    const int*   graph   = (const int*)d_in[1];
    const float* W0      = (const float*)d_in[2];
    const float* W1      = (const float*)d_in[3];
    const float* bias    = (const float*)d_in[4];
    const float* dp_Wa   = (const float*)d_in[5];
    const float* dp_ba   = (const float*)d_in[6];
    const float* dp_Wb   = (const float*)d_in[7];
    const float* dp_bb   = (const float*)d_in[8];
    float* out = (float*)d_out;

    char* w = (char*)d_ws;
    __bf16* fb16  = (__bf16*)(w);                    // 1600*1024*2 = 3,276,800
    __bf16* wcat  = (__bf16*)(w + 3276800);          // 3072*1024*2 = 6,291,456
    __bf16* biasB = (__bf16*)(w + 9568256);          // 2000*1024*2 = 4,096,000
    float*  out0  = (float*)(w + 13664256);          // 6,553,600
    float*  aB    = (float*)(w + 20217856);          // 6,553,600
    float*  bB    = (float*)(w + 26771456);          // 6,553,600
    float*  wl    = (float*)(w + 33325056);          // 6,400
    float*  cwG   = (float*)(w + 33331456);          // 153,600 (end 33,485,056)

    k_prep<<<3336, 256, 0, stream>>>(feature, W0, W1, dp_Wa, dp_Wb, bias,
                                     fb16, wcat, biasB);
    k_gemm<<<600, 256, 0, stream>>>(fb16, wcat, feature, dp_ba, dp_bb,
                                    out0, aB, bB);
    k_ga<<<2000, 256, 0, stream>>>(graph, aB, bB, biasB, out0, wl, cwG);
    k_mix<<<dim3(B_, 4), 256, 0, stream>>>(graph, wl, cwG, out0, out);
}

// Round 16
// 172.707 us; speedup vs baseline: 1.0296x; 1.0296x over previous
//
#include <hip/hip_runtime.h>
#include <stdint.h>

#define B_   16
#define N_   100
#define D_   1024
#define L_   2000
#define M_   1600      // B_*N_
#define KP   2048      // padded label-dim for bias GEMM

#define RCAP 24
#define ZMAX 2400
#define TC   12        // task chunk in k_mix (static unroll bound — keeps acc[] in VGPRs)

typedef __bf16 bf16x8 __attribute__((ext_vector_type(8)));
typedef float  f32x4  __attribute__((ext_vector_type(4)));

__device__ __forceinline__ void gl_lds16(const __bf16* g, __bf16* l) {
    __builtin_amdgcn_global_load_lds(
        (const __attribute__((address_space(1))) void*)g,
        (__attribute__((address_space(3))) void*)l, 16, 0, 0);
}

// ---------------- prep: cvt (feature, wcat) + bias transpose + graph histogram ----------------

__global__ void __launch_bounds__(256)
k_prep(const float* __restrict__ f,
       const float* __restrict__ W0, const float* __restrict__ W1,
       const float* __restrict__ Wa, const float* __restrict__ Wb,
       const float* __restrict__ bias, const int* __restrict__ graph,
       __bf16* __restrict__ fb, __bf16* __restrict__ wcat,
       __bf16* __restrict__ biasBT, __bf16* __restrict__ cnt) {
    int bid = blockIdx.x, t = threadIdx.x;
    __shared__ float lds[32][33];
    __shared__ unsigned int hist[KP];

    if (bid < 2336) {
        int i = bid * 256 + t;               // < 598016 exactly
        union { __bf16 h[8]; uint4 u; } pk;
        if (i < 204800) {
            long base = (long)i * 8;
            const float4* p = (const float4*)(f + base);
            float4 x = p[0], y = p[1];
            pk.h[0]=(__bf16)x.x; pk.h[1]=(__bf16)x.y; pk.h[2]=(__bf16)x.z; pk.h[3]=(__bf16)x.w;
            pk.h[4]=(__bf16)y.x; pk.h[5]=(__bf16)y.y; pk.h[6]=(__bf16)y.z; pk.h[7]=(__bf16)y.w;
            ((uint4*)fb)[i] = pk.u;
        } else {
            int j = i - 204800;
            long base = (long)j * 8;
            long seg = base >> 20;
            long off = base & ((1l << 20) - 1);
            if (seg == 0) {
                const float4* p0 = (const float4*)(W0 + off);
                const float4* p1 = (const float4*)(W1 + off);
                float4 a0 = p0[0], a1 = p0[1], b0 = p1[0], b1 = p1[1];
                pk.h[0]=(__bf16)(a0.x+b0.x); pk.h[1]=(__bf16)(a0.y+b0.y);
                pk.h[2]=(__bf16)(a0.z+b0.z); pk.h[3]=(__bf16)(a0.w+b0.w);
                pk.h[4]=(__bf16)(a1.x+b1.x); pk.h[5]=(__bf16)(a1.y+b1.y);
                pk.h[6]=(__bf16)(a1.z+b1.z); pk.h[7]=(__bf16)(a1.w+b1.w);
            } else {
                const float* src = (seg == 1) ? Wa : Wb;
                const float4* p = (const float4*)(src + off);
                float4 x = p[0], y = p[1];
                pk.h[0]=(__bf16)x.x; pk.h[1]=(__bf16)x.y; pk.h[2]=(__bf16)x.z; pk.h[3]=(__bf16)x.w;
                pk.h[4]=(__bf16)y.x; pk.h[5]=(__bf16)y.y; pk.h[6]=(__bf16)y.z; pk.h[7]=(__bf16)y.w;
            }
            ((uint4*)wcat)[j] = pk.u;
        }
    } else if (bid < 4384) {
        int tb = bid - 2336;                 // 2048 blocks: lt<64, dt<32
        int lt = tb >> 5, dt = tb & 31;
        int l0 = lt * 32, d0 = dt * 32;
        int r = t >> 3, cq = (t & 7) * 4;
        float4 v = make_float4(0.f, 0.f, 0.f, 0.f);
        if (l0 + r < L_) v = *(const float4*)(bias + (long)(l0 + r) * D_ + d0 + cq);
        lds[r][cq]=v.x; lds[r][cq+1]=v.y; lds[r][cq+2]=v.z; lds[r][cq+3]=v.w;
        __syncthreads();
        union { __bf16 h[4]; uint2 u; } pk;
        #pragma unroll
        for (int q = 0; q < 4; ++q) pk.h[q] = (__bf16)lds[cq + q][r];
        *(uint2*)(biasBT + (long)(d0 + r) * KP + l0 + cq) = pk.u;
    } else {
        int m = bid - 4384;                  // 1600 blocks
        for (int k = t; k < KP; k += 256) hist[k] = 0u;
        __syncthreads();
        if (t < N_) atomicAdd(&hist[graph[(long)m * N_ + t]], 1u);
        __syncthreads();
        union { __bf16 h[8]; uint4 u; } pk;
        #pragma unroll
        for (int q = 0; q < 8; ++q) pk.h[q] = (__bf16)(float)hist[t * 8 + q];
        ((uint4*)(cnt + (long)m * KP))[t] = pk.u;
    }
}

// -------- merged GEMM dispatch (R10 config, LPT-reordered: long bias blocks FIRST) --------
// blocks [0,200):   bias [1600x1024] = cnt @ biasBT^T (32 K-iters — longest jobs first)
// blocks [200,800): main [1600x3072] = fb @ wcat^T (16 K-iters)
// XCD-aware swizzle preserved within each range.

#define BM 64
#define BN 128
#define BK 64

__global__ void __launch_bounds__(256)
k_gemmAll(const __bf16* __restrict__ fb, const __bf16* __restrict__ wcat,
          const __bf16* __restrict__ cnt, const __bf16* __restrict__ biasBT,
          const float* __restrict__ feat, const float* __restrict__ ba,
          const float* __restrict__ bbias,
          float* __restrict__ out0, float* __restrict__ aB, float* __restrict__ bB,
          float* __restrict__ out0add) {
    __shared__ __align__(16) __bf16 As[BM * BK];   // 8 KB
    __shared__ __align__(16) __bf16 Bs[BN * BK];   // 16 KB
    int t = threadIdx.x;
    int pid = blockIdx.x;
    int lane = t & 63, wave = t >> 6;
    int wr = wave & 1, wc = wave >> 1;
    int lrow = lane & 15, quad = lane >> 4;

    bool isBias = pid < 200;
    int bm, bn, lda, K;
    const __bf16 *Ag, *Bg;
    if (isBias) {
        int v = (pid & 7) * 25 + (pid >> 3);       // [0,200) unique
        bm = v >> 3; bn = v & 7;                   // per-XCD: bm ~3 contiguous
        Ag = cnt    + (long)(bm * BM) * KP;
        Bg = biasBT + (long)(bn * BN) * KP;
        lda = KP; K = KP;
    } else {
        int p2 = pid - 200;                        // [0,600)
        int v = (p2 & 7) * 75 + (p2 >> 3);         // [0,600) unique
        bn = v / 25; bm = v % 25;                  // per-XCD: bn in [3x,3x+3)
        Ag = fb   + (long)(bm * BM) * D_;
        Bg = wcat + (long)(bn * BN) * D_;
        lda = D_; K = D_;
    }

    f32x4 acc[2][4] = {};
    for (int k0 = 0; k0 < K; k0 += BK) {
        #pragma unroll
        for (int pi = 0; pi < 2; ++pi) {
            int p = pi * 256 + t, row = p >> 3, c = (p & 7) ^ (row & 7);
            gl_lds16(Ag + (long)row * lda + k0 + c * 8, As + p * 8);
        }
        #pragma unroll
        for (int pi = 0; pi < 4; ++pi) {
            int p = pi * 256 + t, row = p >> 3, c = (p & 7) ^ (row & 7);
            gl_lds16(Bg + (long)row * lda + k0 + c * 8, Bs + p * 8);
        }
        __syncthreads();
        #pragma unroll
        for (int ks = 0; ks < 2; ++ks) {
            bf16x8 af[2], bf[4];
            #pragma unroll
            for (int i = 0; i < 2; ++i) {
                int r = wr * 32 + i * 16 + lrow;
                int slot = r * 8 + (((ks << 2) | quad) ^ (r & 7));
                af[i] = *(const bf16x8*)(As + slot * 8);
            }
            #pragma unroll
            for (int j = 0; j < 4; ++j) {
                int r = wc * 64 + j * 16 + lrow;
                int slot = r * 8 + (((ks << 2) | quad) ^ (r & 7));
                bf[j] = *(const bf16x8*)(Bs + slot * 8);
            }
            #pragma unroll
            for (int i = 0; i < 2; ++i)
                #pragma unroll
                for (int j = 0; j < 4; ++j)
                    acc[i][j] = __builtin_amdgcn_mfma_f32_16x16x32_bf16(af[i], bf[j], acc[i][j], 0, 0, 0);
        }
        __syncthreads();
    }

    if (!isBias) {
        int nbase = bn * BN;
        int seg = bn >> 3;
        #pragma unroll
        for (int i = 0; i < 2; ++i) {
            int gm0 = bm * BM + wr * 32 + i * 16 + quad * 4;
            #pragma unroll
            for (int j = 0; j < 4; ++j) {
                int col = (nbase + wc * 64 + j * 16 + lrow) & 1023;
                #pragma unroll
                for (int r = 0; r < 4; ++r) {
                    long m = gm0 + r;
                    float v = acc[i][j][r];
                    if (seg == 0)      out0[m * D_ + col] = v + feat[m * D_ + col];
                    else if (seg == 1) aB[m * D_ + col]   = v + ba[col];
                    else               bB[m * D_ + col]   = v + bbias[col];
                }
            }
        }
    } else {
        #pragma unroll
        for (int i = 0; i < 2; ++i) {
            int gm0 = bm * BM + wr * 32 + i * 16 + quad * 4;
            #pragma unroll
            for (int j = 0; j < 4; ++j) {
                int col = bn * BN + wc * 64 + j * 16 + lrow;
                #pragma unroll
                for (int r = 0; r < 4; ++r) {
                    long m = gm0 + r;
                    out0add[m * D_ + col] = acc[i][j][r];
                }
            }
        }
    }
}

// ---------------- alpha: deterministic self-scan + corr -> per-column weights ----------------
// block pid -> (b, kc): 4 columns k = kc*4+{0..3}. Dirty rows ranked by increasing row index.

__global__ void __launch_bounds__(256)
k_alpha(const int* __restrict__ graph, const float* __restrict__ aB,
        const float* __restrict__ bB, float* __restrict__ wl, float* __restrict__ cwG) {
    __shared__ int rowCnt[N_], rowOff[N_], rowRank[N_];
    __shared__ int ndvS, totZS;
    __shared__ int zjL[ZMAX];
    __shared__ short prL[ZMAX];
    __shared__ float corrL[RCAP][4];
    __shared__ float wred[4][4];

    int pid = blockIdx.x;                    // 0..399
    int b = pid / 25, kc = pid - b * 25;
    int t = threadIdx.x, lane = t & 63, wave = t >> 6;

    const int* g = graph + (long)b * N_ * N_;
    if (t < N_) {
        int c = 0;
        for (int j = 0; j < N_; ++j) if (g[t * N_ + j] == 0) ++c;
        rowCnt[t] = c;
    }
    if (t < RCAP * 4) corrL[t >> 2][t & 3] = 0.f;
    __syncthreads();
    if (t == 0) {
        int off = 0, rank = 0;
        for (int i = 0; i < N_; ++i) {
            if (rowCnt[i] > 0 && rank < RCAP) {
                rowRank[i] = rank; rowOff[i] = off; off += rowCnt[i]; ++rank;
            } else rowRank[i] = -1;
        }
        ndvS = rank; totZS = off;
    }
    __syncthreads();
    if (t < N_ && rowRank[t] >= 0) {
        int pos = rowOff[t], r = rowRank[t];
        for (int j = 0; j < N_; ++j)
            if (g[t * N_ + j] == 0) { zjL[pos] = j; prL[pos] = (short)r; ++pos; }
    }
    __syncthreads();
    int Z = totZS, ndv = ndvS;

    int k0 = kc * 4;
    float4 bv[4];
    #pragma unroll
    for (int kk = 0; kk < 4; ++kk)
        bv[kk] = *(const float4*)(bB + ((long)(b * N_ + k0 + kk)) * D_ + t * 4);

    for (int q = 0; q < Z; ++q) {
        const float* ar = aB + ((long)(b * N_ + zjL[q])) * D_;
        float4 av = *(const float4*)(ar + t * 4);
        float s[4];
        #pragma unroll
        for (int kk = 0; kk < 4; ++kk)
            s[kk] = av.x * bv[kk].x + av.y * bv[kk].y + av.z * bv[kk].z + av.w * bv[kk].w;
        #pragma unroll
        for (int off = 32; off > 0; off >>= 1)
            #pragma unroll
            for (int kk = 0; kk < 4; ++kk) s[kk] += __shfl_xor(s[kk], off);
        if (lane == 0) { wred[wave][0]=s[0]; wred[wave][1]=s[1]; wred[wave][2]=s[2]; wred[wave][3]=s[3]; }
        __syncthreads();
        if (t < 4) {
            float v = wred[0][t] + wred[1][t] + wred[2][t] + wred[3][t];
            corrL[prL[q]][t] += fmaxf(v, 0.f);
        }
        __syncthreads();
    }

    if (t < 4) {
        int k = k0 + t;
        float denom = (float)(N_ - ndv);
        for (int r = 0; r < ndv; ++r) {
            float e = __expf(-corrL[r][t]);
            corrL[r][t] = e;
            denom += e;
        }
        float w = 1.f / denom;
        wl[b * N_ + k] = w;
        for (int r = 0; r < ndv; ++r)
            cwG[((long)b * RCAP + r) * N_ + k] = corrL[r][t] * w;
    }
}

// ---------------- mix: out rows = weighted sums of (out0 + out0add) rows (float4) -----------

__global__ void __launch_bounds__(256)
k_mix(const int* __restrict__ graph, const float* __restrict__ wl,
      const float* __restrict__ cwG, const float* __restrict__ out0,
      const float* __restrict__ out0add, float* __restrict__ out) {
    int b = blockIdx.x, dq = blockIdx.y;
    int t = threadIdx.x, c4 = t & 63, q = t >> 6;
    int d0 = dq * 256;
    __shared__ int hasZ[N_], mapL[N_], ndvS;
    __shared__ float wT[TC][N_];
    __shared__ f32x4 parts[4][TC][64];

    const int* g = graph + (long)b * N_ * N_;
    if (t < N_) {
        int z = 0;
        for (int j = 0; j < N_; ++j) if (g[t * N_ + j] == 0) { z = 1; break; }
        hasZ[t] = z;
    }
    __syncthreads();
    if (t < N_) {
        int rank = 0;
        for (int i = 0; i < t; ++i) rank += hasZ[i];
        mapL[t] = (hasZ[t] && rank < RCAP) ? 1 + rank : 0;
    }
    if (t == 0) {
        int n = 0;
        for (int i = 0; i < N_; ++i) n += hasZ[i];
        ndvS = min(n, RCAP);
    }
    __syncthreads();
    int ndv = ndvS, ntask = ndv + 1;

    const float* o0 = out0    + (long)b * N_ * D_ + d0;
    const float* oa = out0add + (long)b * N_ * D_ + d0;
    for (int cb = 0; cb < ntask; cb += TC) {
        for (int idx = t; idx < TC * N_; idx += 256) {
            int rr = idx / N_, j = idx - rr * N_;
            int task = cb + rr;
            float v = 0.f;
            if (task == 0)         v = wl[b * N_ + j];
            else if (task <= ndv)  v = cwG[((long)b * RCAP + task - 1) * N_ + j];
            wT[rr][j] = v;
        }
        __syncthreads();
        f32x4 acc[TC] = {};
        for (int j = q * 25; j < q * 25 + 25; ++j) {
            f32x4 v = *(const f32x4*)(o0 + (long)j * D_ + c4 * 4)
                    + *(const f32x4*)(oa + (long)j * D_ + c4 * 4);
            #pragma unroll
            for (int rr = 0; rr < TC; ++rr) acc[rr] += wT[rr][j] * v;
        }
        #pragma unroll
        for (int rr = 0; rr < TC; ++rr) parts[q][rr][c4] = acc[rr];
        __syncthreads();
        for (int i = q * 25; i < q * 25 + 25; ++i) {
            int task = mapL[i];
            if (task >= cb && task < cb + TC) {
                int rr = task - cb;
                f32x4 s = parts[0][rr][c4] + parts[1][rr][c4]
                        + parts[2][rr][c4] + parts[3][rr][c4];
                *(f32x4*)(out + ((long)(b * N_ + i)) * D_ + d0 + c4 * 4) = s;
            }
        }
        __syncthreads();
    }
}

// ---------------- launch ----------------

extern "C" void kernel_launch(void* const* d_in, const int* in_sizes, int n_in,
                              void* d_out, int out_size, void* d_ws, size_t ws_size,
                              hipStream_t stream) {
    const float* feature = (const float*)d_in[0];
    const int*   graph   = (const int*)d_in[1];
    const float* W0      = (const float*)d_in[2];
    const float* W1      = (const float*)d_in[3];
    const float* bias    = (const float*)d_in[4];
    const float* dp_Wa   = (const float*)d_in[5];
    const float* dp_ba   = (const float*)d_in[6];
    const float* dp_Wb   = (const float*)d_in[7];
    const float* dp_bb   = (const float*)d_in[8];
    float* out = (float*)d_out;

    char* w = (char*)d_ws;
    __bf16* fb16    = (__bf16*)(w);                  // 1600*1024*2 = 3,276,800
    __bf16* wcat    = (__bf16*)(w + 3276800);        // 3072*1024*2 = 6,291,456
    __bf16* cnt     = (__bf16*)(w + 9568256);        // 1600*2048*2 = 6,553,600
    __bf16* biasBT  = (__bf16*)(w + 16121856);       // 1024*2048*2 = 4,194,304
    float*  out0    = (float*)(w + 20316160);        // 6,553,600
    float*  aB      = (float*)(w + 26869760);        // 6,553,600
    float*  bB      = (float*)(w + 33423360);        // 6,553,600
    float*  wl      = (float*)(w + 39976960);        // 6,400
    float*  cwG     = (float*)(w + 39983360);        // 153,600
    float*  out0add = (float*)(w + 40136960);        // 6,553,600 (end 46,690,560)

    k_prep<<<5984, 256, 0, stream>>>(feature, W0, W1, dp_Wa, dp_Wb, bias, graph,
                                     fb16, wcat, biasBT, cnt);
    k_gemmAll<<<800, 256, 0, stream>>>(fb16, wcat, cnt, biasBT, feature, dp_ba, dp_bb,
                                       out0, aB, bB, out0add);
    k_alpha<<<400, 256, 0, stream>>>(graph, aB, bB, wl, cwG);
    k_mix<<<dim3(B_, 4), 256, 0, stream>>>(graph, wl, cwG, out0, out0add, out);
}